// Round 3
// baseline (240.119 us; speedup 1.0000x reference)
//
#include <hip/hip_runtime.h>
#include <hip/hip_cooperative_groups.h>

namespace cg = cooperative_groups;

#define N_NODES 10000
#define IN_DIM  256
#define OUT_DIM 64
#define ALPHA   0.2f
#define CAPS    128    // slot capacity/row (mean deg 32, max ~66; P(>128) ~ 1e-40, clamped)
#define NBLK    625    // 625 blocks x 16 rows = 10000 rows exactly
#define NTHR    256
#define NWAVES  (NBLK * 4)

// ---------------------------------------------------------------------------
// ONE cooperative kernel, 3 phases separated by grid.sync():
//   P1: Wh = X@W (16 rows/block, LDS-staged X, lane=outcol), es/ed scores,
//       zero cur[]
//   P2: scatter edges into fixed-stride per-row buckets {dst, ed[dst]}
//   P3: per-wave row softmax + PV, fully in-register (shfl broadcasts,
//       no LDS, no __syncthreads -> no divergence hazard across waves)
// ---------------------------------------------------------------------------
__global__ __launch_bounds__(NTHR, 3) void k_fused(
    const float* __restrict__ X, const int* __restrict__ src,
    const int* __restrict__ dst, int E,
    const float* __restrict__ W, const float* __restrict__ a,
    float* __restrict__ Wh, float* __restrict__ es, float* __restrict__ ed,
    int* __restrict__ cur, int2* __restrict__ slots, float* __restrict__ out)
{
    cg::grid_group grid = cg::this_grid();
    const int t = threadIdx.x;
    const int b = blockIdx.x;
    const int wave = t >> 6, lane = t & 63;
    const int gid = b * NTHR + t;

    // ---------------- phase 1: GEMM + scores (+ zero counters) ----------------
    if (gid < N_NODES) cur[gid] = 0;

    __shared__ __align__(16) float xs[16][IN_DIM];   // 16 KB
    const int base = b * 16;                          // 625*16 == 10000 exactly
    for (int i = t; i < 16 * (IN_DIM / 4); i += NTHR) {
        int r = i >> 6, c4 = i & 63;
        ((float4*)&xs[r][0])[c4] =
            ((const float4*)X)[(size_t)(base + r) * (IN_DIM / 4) + c4];
    }
    __syncthreads();

    float acc[4] = {0.f, 0.f, 0.f, 0.f};
    for (int kk = 0; kk < IN_DIM; kk += 4) {
        float w0 = W[(kk + 0) * OUT_DIM + lane];   // 256B coalesced, L2-resident
        float w1 = W[(kk + 1) * OUT_DIM + lane];
        float w2 = W[(kk + 2) * OUT_DIM + lane];
        float w3 = W[(kk + 3) * OUT_DIM + lane];
#pragma unroll
        for (int r4 = 0; r4 < 4; ++r4) {
            float4 xv = *(const float4*)&xs[wave * 4 + r4][kk];  // LDS b128 broadcast
            acc[r4] = fmaf(xv.x, w0, acc[r4]);
            acc[r4] = fmaf(xv.y, w1, acc[r4]);
            acc[r4] = fmaf(xv.z, w2, acc[r4]);
            acc[r4] = fmaf(xv.w, w3, acc[r4]);
        }
    }

    const float asrc = a[lane];
    const float adst = a[OUT_DIM + lane];
#pragma unroll
    for (int r4 = 0; r4 < 4; ++r4) {
        int row = base + wave * 4 + r4;
        float v = acc[r4];
        Wh[(size_t)row * OUT_DIM + lane] = v;
        float s1 = v * asrc;
        float s2 = v * adst;
#pragma unroll
        for (int o = 32; o > 0; o >>= 1) {
            s1 += __shfl_xor(s1, o, 64);
            s2 += __shfl_xor(s2, o, 64);
        }
        if (lane == 0) { es[row] = s1; ed[row] = s2; }
    }

    grid.sync();

    // ---------------- phase 2: bucket-scatter edges ----------------
    for (int i = gid; i < E; i += NBLK * NTHR) {
        int s = src[i], d = dst[i];
        float ev = ed[d];                       // 40KB table, cache-resident
        int p = atomicAdd(&cur[s], 1);
        if (p < CAPS) slots[(size_t)s * CAPS + p] = make_int2(d, __float_as_int(ev));
    }

    grid.sync();

    // ---------------- phase 3: per-wave row softmax + PV (register-only) ------
    const int gw = b * 4 + wave;
    for (int r = gw; r < N_NODES; r += NWAVES) {
        int deg = cur[r];
        if (deg > CAPS) deg = CAPS;
        const float er = es[r];

        // lane holds slots i=lane (A) and i=64+lane (B)
        int d0 = -1, d1 = -1;
        float e0 = -INFINITY, e1 = -INFINITY;
        if (lane < deg) {
            int2 v = slots[(size_t)r * CAPS + lane];
            d0 = v.x;
            float e = er + __int_as_float(v.y);
            e0 = e > 0.f ? e : ALPHA * e;
        }
        if (64 + lane < deg) {
            int2 v = slots[(size_t)r * CAPS + 64 + lane];
            d1 = v.x;
            float e = er + __int_as_float(v.y);
            e1 = e > 0.f ? e : ALPHA * e;
        }

        // dedupe: slot i is kept iff no j<i has same dst (ref .at[].set counts
        // each (src,dst) pair once; duplicate e-values identical)
        bool dup0 = false, dup1 = false;
        int jmax0 = deg < 64 ? deg : 64;
        for (int j = 0; j < jmax0; ++j) {
            int dj = __shfl(d0, j, 64);
            if (j < lane && dj == d0) dup0 = true;
            if (dj == d1) dup1 = true;          // all j<64 precede i=64+lane
        }
        for (int j = 64; j < deg; ++j) {
            int dj = __shfl(d1, j - 64, 64);
            if ((j - 64) < lane && dj == d1) dup1 = true;
        }
        if (dup0) e0 = -INFINITY;
        if (dup1) e1 = -INFINITY;

        float m = fmaxf(e0, e1);
#pragma unroll
        for (int o = 32; o > 0; o >>= 1) m = fmaxf(m, __shfl_xor(m, o, 64));

        float p0 = __expf(e0 - m);   // -inf slots -> 0 (m finite when deg>0)
        float p1 = __expf(e1 - m);
        float ssum = p0 + p1;
#pragma unroll
        for (int o = 32; o > 0; o >>= 1) ssum += __shfl_xor(ssum, o, 64);

        float acc3 = 0.f;
        for (int j = 0; j < deg; ++j) {
            float pj = __shfl(j < 64 ? p0 : p1, j & 63, 64);  // uniform broadcast
            int   dj = __shfl(j < 64 ? d0 : d1, j & 63, 64);
            if (pj > 0.f)                                     // uniform branch
                acc3 = fmaf(pj, Wh[(size_t)dj * OUT_DIM + lane], acc3);
        }

        if (deg == 0) {
            // softmax of all-NEG_FILL row is uniform -> column mean of Wh
            float cm = 0.f;
            for (int jj = 0; jj < N_NODES; ++jj) cm += Wh[(size_t)jj * OUT_DIM + lane];
            out[(size_t)r * OUT_DIM + lane] = cm / (float)N_NODES;
        } else {
            out[(size_t)r * OUT_DIM + lane] = acc3 / ssum;
        }
    }
}

// ---------------------------------------------------------------------------
// Fallback (ws too small for slots): proven round-2 three-kernel path.
// ---------------------------------------------------------------------------
__global__ __launch_bounds__(256) void k_gemm(const float* __restrict__ X,
                                              const float* __restrict__ W,
                                              const float* __restrict__ a,
                                              float* __restrict__ Wh,
                                              float* __restrict__ es,
                                              float* __restrict__ ed,
                                              int* __restrict__ zero10k) {
    const int t = threadIdx.x;
    const int gid = blockIdx.x * 256 + t;
    if (gid < N_NODES) zero10k[gid] = 0;
    __shared__ __align__(16) float xs[32][IN_DIM];
    const int wave = t >> 6, lane = t & 63;
    const int base = blockIdx.x * 32;
    for (int i = t; i < 32 * (IN_DIM / 4); i += 256) {
        int r = i >> 6, c4 = i & 63;
        int row = base + r;
        float4 v = (row < N_NODES) ? ((const float4*)X)[(size_t)row * (IN_DIM / 4) + c4]
                                   : make_float4(0.f, 0.f, 0.f, 0.f);
        ((float4*)&xs[r][0])[c4] = v;
    }
    __syncthreads();
    float acc[8];
#pragma unroll
    for (int i = 0; i < 8; ++i) acc[i] = 0.f;
    for (int kk = 0; kk < IN_DIM; kk += 4) {
        float w0 = W[(kk + 0) * OUT_DIM + lane];
        float w1 = W[(kk + 1) * OUT_DIM + lane];
        float w2 = W[(kk + 2) * OUT_DIM + lane];
        float w3 = W[(kk + 3) * OUT_DIM + lane];
#pragma unroll
        for (int r8 = 0; r8 < 8; ++r8) {
            float4 xv = *(const float4*)&xs[wave * 8 + r8][kk];
            acc[r8] = fmaf(xv.x, w0, acc[r8]);
            acc[r8] = fmaf(xv.y, w1, acc[r8]);
            acc[r8] = fmaf(xv.z, w2, acc[r8]);
            acc[r8] = fmaf(xv.w, w3, acc[r8]);
        }
    }
    const float asrc = a[lane];
    const float adst = a[OUT_DIM + lane];
#pragma unroll
    for (int r8 = 0; r8 < 8; ++r8) {
        int row = base + wave * 8 + r8;
        if (row < N_NODES) {
            float v = acc[r8];
            Wh[(size_t)row * OUT_DIM + lane] = v;
            float s1 = v * asrc, s2 = v * adst;
#pragma unroll
            for (int o = 32; o > 0; o >>= 1) {
                s1 += __shfl_xor(s1, o, 64);
                s2 += __shfl_xor(s2, o, 64);
            }
            if (lane == 0) { es[row] = s1; ed[row] = s2; }
        }
    }
}

__global__ void k_fill_slots(const int* __restrict__ src, const int* __restrict__ dst,
                             int E, const float* __restrict__ ed,
                             int* __restrict__ cur, int2* __restrict__ slots) {
    int i = blockIdx.x * 256 + threadIdx.x;
    if (i < E) {
        int s = src[i], d = dst[i];
        float ev = ed[d];
        int p = atomicAdd(&cur[s], 1);
        if (p < CAPS) slots[(size_t)s * CAPS + p] = make_int2(d, __float_as_int(ev));
    }
}

__global__ __launch_bounds__(64) void k_attn_slots(const int* __restrict__ cur,
                                                   const int2* __restrict__ slots,
                                                   const float* __restrict__ es,
                                                   const float* __restrict__ Wh,
                                                   float* __restrict__ out) {
    const int r = blockIdx.x;
    const int lane = threadIdx.x;
    int deg = cur[r];
    if (deg > CAPS) deg = CAPS;
    if (deg == 0) {
        float acc = 0.f;
        for (int j = 0; j < N_NODES; ++j) acc += Wh[(size_t)j * OUT_DIM + lane];
        out[(size_t)r * OUT_DIM + lane] = acc / (float)N_NODES;
        return;
    }
    const float er = es[r];
    __shared__ int   sdst[CAPS];
    __shared__ float sp[CAPS];
    for (int i = lane; i < deg; i += 64) {
        int2 v = slots[(size_t)r * CAPS + i];
        sdst[i] = v.x;
        float e = er + __int_as_float(v.y);
        sp[i] = e > 0.f ? e : ALPHA * e;
    }
    __syncthreads();
    float m = -INFINITY;
    for (int i = lane; i < deg; i += 64) {
        int d = sdst[i];
        bool first = true;
        for (int j = 0; j < i; ++j)
            if (sdst[j] == d) { first = false; break; }
        if (first) m = fmaxf(m, sp[i]);
        else       sp[i] = -INFINITY;
    }
#pragma unroll
    for (int o = 32; o > 0; o >>= 1) m = fmaxf(m, __shfl_xor(m, o, 64));
    __syncthreads();
    float ssum = 0.f;
    for (int i = lane; i < deg; i += 64) {
        float p = __expf(sp[i] - m);
        sp[i] = p;
        ssum += p;
    }
#pragma unroll
    for (int o = 32; o > 0; o >>= 1) ssum += __shfl_xor(ssum, o, 64);
    __syncthreads();
    float acc = 0.f;
    for (int i = 0; i < deg; ++i)
        acc = fmaf(sp[i], Wh[(size_t)sdst[i] * OUT_DIM + lane], acc);
    out[(size_t)r * OUT_DIM + lane] = acc / ssum;
}

// ---------------------------------------------------------------------------
extern "C" void kernel_launch(void* const* d_in, const int* in_sizes, int n_in,
                              void* d_out, int out_size, void* d_ws, size_t ws_size,
                              hipStream_t stream) {
    const float* X     = (const float*)d_in[0];
    const int*   edges = (const int*)d_in[1];
    const float* W     = (const float*)d_in[2];
    const float* a     = (const float*)d_in[3];
    float* out = (float*)d_out;

    const int E = in_sizes[1] / 2;
    const int* src = edges;
    const int* dst = edges + E;

    char* ws = (char*)d_ws;
    size_t o = 0;
    auto carve = [&](size_t bytes) -> void* {
        o = (o + 255) & ~(size_t)255;
        void* p = ws + o;
        o += bytes;
        return p;
    };
    float* Wh  = (float*)carve((size_t)N_NODES * OUT_DIM * 4);
    float* es  = (float*)carve((size_t)N_NODES * 4);
    float* ed  = (float*)carve((size_t)N_NODES * 4);
    int*   cur = (int*)carve((size_t)N_NODES * 4);
    int2*  slots = (int2*)carve((size_t)N_NODES * CAPS * 8);

    if (o <= ws_size) {
        void* args[] = {(void*)&X, (void*)&src, (void*)&dst, (void*)&E,
                        (void*)&W, (void*)&a, (void*)&Wh, (void*)&es,
                        (void*)&ed, (void*)&cur, (void*)&slots, (void*)&out};
        hipLaunchCooperativeKernel((const void*)k_fused, dim3(NBLK), dim3(NTHR),
                                   args, 0, stream);
    } else {
        // fallback: three-kernel slot path (round-2 proven)
        k_gemm      <<<(N_NODES + 31) / 32, 256, 0, stream>>>(X, W, a, Wh, es, ed, cur);
        k_fill_slots<<<(E + 255) / 256, 256, 0, stream>>>(src, dst, E, ed, cur, slots);
        k_attn_slots<<<N_NODES, 64, 0, stream>>>(cur, slots, es, Wh, out);
    }
}

// Round 4
// 69.981 us; speedup vs baseline: 3.4312x; 3.4312x over previous
//
#include <hip/hip_runtime.h>

#define N_NODES 10000
#define IN_DIM  256
#define OUT_DIM 64
#define ALPHA   0.2f
#define CAPS    128   // slot capacity/row (mean deg 32, max ~66; P(>128) ~ 1e-40, clamped)
#define CAP     256   // CSR-fallback LDS edge capacity

// ---------------------------------------------------------------------------
// Kernel 1: Wh = X @ W  (N x 256 @ 256 x 64), fused with per-node scores
//           es[n] = Wh[n,:] . a[0:64],  ed[n] = Wh[n,:] . a[64:128]
// Also zeroes cur[] for k_fill_slots (saves a fill dispatch).
// 32 rows/block, 8 rows/wave, lane = out column. NOTE (round-3 lesson):
// do NOT fuse these phases with grid.sync() — cooperative sync on 8-XCD
// MI355X flushes L2 and serialized the gather phase (69us -> 240us).
// ---------------------------------------------------------------------------
__global__ __launch_bounds__(256) void k_gemm(const float* __restrict__ X,
                                              const float* __restrict__ W,
                                              const float* __restrict__ a,
                                              float* __restrict__ Wh,
                                              float* __restrict__ es,
                                              float* __restrict__ ed,
                                              int* __restrict__ zero10k) {
    const int t = threadIdx.x;
    const int gid = blockIdx.x * 256 + t;
    if (gid < N_NODES) zero10k[gid] = 0;

    __shared__ __align__(16) float xs[32][IN_DIM];   // 32 KB
    const int wave = t >> 6, lane = t & 63;
    const int base = blockIdx.x * 32;

    for (int i = t; i < 32 * (IN_DIM / 4); i += 256) {
        int r = i >> 6, c4 = i & 63;
        int row = base + r;
        float4 v = (row < N_NODES) ? ((const float4*)X)[(size_t)row * (IN_DIM / 4) + c4]
                                   : make_float4(0.f, 0.f, 0.f, 0.f);
        ((float4*)&xs[r][0])[c4] = v;
    }
    __syncthreads();

    float acc[8];
#pragma unroll
    for (int i = 0; i < 8; ++i) acc[i] = 0.f;

    for (int kk = 0; kk < IN_DIM; kk += 4) {
        float w0 = W[(kk + 0) * OUT_DIM + lane];   // 256B coalesced, L1/L2-resident
        float w1 = W[(kk + 1) * OUT_DIM + lane];
        float w2 = W[(kk + 2) * OUT_DIM + lane];
        float w3 = W[(kk + 3) * OUT_DIM + lane];
#pragma unroll
        for (int r8 = 0; r8 < 8; ++r8) {
            float4 xv = *(const float4*)&xs[wave * 8 + r8][kk];  // LDS b128 broadcast
            acc[r8] = fmaf(xv.x, w0, acc[r8]);
            acc[r8] = fmaf(xv.y, w1, acc[r8]);
            acc[r8] = fmaf(xv.z, w2, acc[r8]);
            acc[r8] = fmaf(xv.w, w3, acc[r8]);
        }
    }

    const float asrc = a[lane];
    const float adst = a[OUT_DIM + lane];
#pragma unroll
    for (int r8 = 0; r8 < 8; ++r8) {
        int row = base + wave * 8 + r8;
        if (row < N_NODES) {
            float v = acc[r8];
            Wh[(size_t)row * OUT_DIM + lane] = v;
            float s1 = v * asrc, s2 = v * adst;
#pragma unroll
            for (int o = 32; o > 0; o >>= 1) {
                s1 += __shfl_xor(s1, o, 64);
                s2 += __shfl_xor(s2, o, 64);
            }
            if (lane == 0) { es[row] = s1; ed[row] = s2; }
        }
    }
}

// ---------------------------------------------------------------------------
// Kernel 2: scatter edges into fixed-stride per-row buckets, storing the
// FINISHED score {dst, e = leakyrelu(es[s]+ed[d])}. es/ed are 40KB tables,
// L1/L2-resident — moving this VALU+gather here (massively parallel, not
// latency-critical) slims the attention kernel.
// ---------------------------------------------------------------------------
__global__ void k_fill_slots(const int* __restrict__ src, const int* __restrict__ dst,
                             int E, const float* __restrict__ es,
                             const float* __restrict__ ed,
                             int* __restrict__ cur, int2* __restrict__ slots) {
    int i = blockIdx.x * 256 + threadIdx.x;
    if (i < E) {
        int s = src[i], d = dst[i];
        float e = es[s] + ed[d];
        e = e > 0.f ? e : ALPHA * e;
        int p = atomicAdd(&cur[s], 1);
        if (p < CAPS) slots[(size_t)s * CAPS + p] = make_int2(d, __float_as_int(e));
    }
}

// ---------------------------------------------------------------------------
// Kernel 3: one wave per row. Dedupe duplicate (src,dst) pairs (reference
// .at[].set counts each unique pair ONCE; duplicate e identical -> which
// duplicate survives is moot), softmax, h' = sum p_i/S * Wh[dst_i,:].
// lane = out dim -> 256B coalesced Wh row gathers.
// Pass D manually unrolled x4: 4 unconditional gathers in flight (the loop
// bound is dynamic so the compiler won't pipeline it on its own).
// ---------------------------------------------------------------------------
__global__ __launch_bounds__(64) void k_attn_slots(const int* __restrict__ cur,
                                                   const int2* __restrict__ slots,
                                                   const float* __restrict__ Wh,
                                                   float* __restrict__ out) {
    const int r = blockIdx.x;
    const int lane = threadIdx.x;
    int deg = cur[r];
    if (deg > CAPS) deg = CAPS;

    if (deg == 0) {
        // softmax of all-NEG_FILL row is uniform -> column mean of Wh
        float acc = 0.f;
        for (int j = 0; j < N_NODES; ++j) acc += Wh[(size_t)j * OUT_DIM + lane];
        out[(size_t)r * OUT_DIM + lane] = acc / (float)N_NODES;
        return;
    }

    __shared__ int   sdst[CAPS];
    __shared__ float sp[CAPS];

    // pass A: load finished slot pairs
    for (int i = lane; i < deg; i += 64) {
        int2 v = slots[(size_t)r * CAPS + i];
        sdst[i] = v.x;
        sp[i]   = __int_as_float(v.y);
    }
    __syncthreads();

    // pass B: dedupe-mark + row max
    float m = -INFINITY;
    for (int i = lane; i < deg; i += 64) {
        int d = sdst[i];
        bool first = true;
        for (int j = 0; j < i; ++j)
            if (sdst[j] == d) { first = false; break; }
        if (first) m = fmaxf(m, sp[i]);
        else       sp[i] = -INFINITY;     // exp() -> 0
    }
#pragma unroll
    for (int o = 32; o > 0; o >>= 1) m = fmaxf(m, __shfl_xor(m, o, 64));
    __syncthreads();

    // pass C: exp + sum
    float ssum = 0.f;
    for (int i = lane; i < deg; i += 64) {
        float p = __expf(sp[i] - m);
        sp[i] = p;
        ssum += p;
    }
#pragma unroll
    for (int o = 32; o > 0; o >>= 1) ssum += __shfl_xor(ssum, o, 64);
    __syncthreads();

    // pass D: accumulate h', 4 gathers in flight
    float acc = 0.f;
    int i = 0;
    for (; i + 4 <= deg; i += 4) {
        float p0 = sp[i + 0], p1 = sp[i + 1], p2 = sp[i + 2], p3 = sp[i + 3];
        int   q0 = sdst[i + 0], q1 = sdst[i + 1], q2 = sdst[i + 2], q3 = sdst[i + 3];
        float w0 = Wh[(size_t)q0 * OUT_DIM + lane];
        float w1 = Wh[(size_t)q1 * OUT_DIM + lane];
        float w2 = Wh[(size_t)q2 * OUT_DIM + lane];
        float w3 = Wh[(size_t)q3 * OUT_DIM + lane];
        acc = fmaf(p0, w0, acc);
        acc = fmaf(p1, w1, acc);
        acc = fmaf(p2, w2, acc);
        acc = fmaf(p3, w3, acc);
    }
    for (; i < deg; ++i)
        acc = fmaf(sp[i], Wh[(size_t)sdst[i] * OUT_DIM + lane], acc);

    out[(size_t)r * OUT_DIM + lane] = acc / ssum;
}

// ---------------------------------------------------------------------------
// CSR FALLBACK (only if ws can't hold the slot buckets) — round-1 proven path.
// ---------------------------------------------------------------------------
__global__ void k_count(const int* __restrict__ src, int E, int* __restrict__ cnt) {
    int i = blockIdx.x * 256 + threadIdx.x;
    if (i < E) atomicAdd(&cnt[src[i]], 1);
}

__global__ __launch_bounds__(1024) void k_scan(const int* __restrict__ cnt,
                                               int* __restrict__ off,
                                               int* __restrict__ cur,
                                               int n, int E) {
    __shared__ int part[1024];
    const int t = threadIdx.x;
    const int CH = (N_NODES + 1023) / 1024;
    int beg = t * CH, end = min(beg + CH, n);
    int s = 0;
    for (int i = beg; i < end; ++i) s += cnt[i];
    part[t] = s;
    __syncthreads();
    for (int d = 1; d < 1024; d <<= 1) {
        int v = (t >= d) ? part[t - d] : 0;
        __syncthreads();
        part[t] += v;
        __syncthreads();
    }
    int run = (t == 0) ? 0 : part[t - 1];
    for (int i = beg; i < end; ++i) {
        off[i] = run;
        cur[i] = run;
        run += cnt[i];
    }
    if (t == 0) off[n] = E;
}

__global__ void k_fill(const int* __restrict__ src, const int* __restrict__ dst, int E,
                       int* __restrict__ cur, int* __restrict__ csr) {
    int i = blockIdx.x * 256 + threadIdx.x;
    if (i < E) {
        int p = atomicAdd(&cur[src[i]], 1);
        csr[p] = dst[i];
    }
}

__global__ __launch_bounds__(64) void k_attn(const int* __restrict__ off,
                                             const int* __restrict__ csr,
                                             const float* __restrict__ es,
                                             const float* __restrict__ ed,
                                             const float* __restrict__ Wh,
                                             float* __restrict__ out) {
    const int r = blockIdx.x;
    const int lane = threadIdx.x;
    const int beg = off[r];
    const int deg = off[r + 1] - beg;
    if (deg == 0) {
        float acc = 0.f;
        for (int j = 0; j < N_NODES; ++j) acc += Wh[(size_t)j * OUT_DIM + lane];
        out[(size_t)r * OUT_DIM + lane] = acc / (float)N_NODES;
        return;
    }
    const float er = es[r];
    __shared__ int   sdst[CAP];
    __shared__ float sp[CAP];
    if (deg <= CAP) {
        for (int i = lane; i < deg; i += 64) sdst[i] = csr[beg + i];
        __syncthreads();
        float m = -INFINITY;
        for (int i = lane; i < deg; i += 64) {
            int d = sdst[i];
            bool first = true;
            for (int j = 0; j < i; ++j)
                if (sdst[j] == d) { first = false; break; }
            float e;
            if (first) {
                e = er + ed[d];
                e = e > 0.f ? e : ALPHA * e;
                m = fmaxf(m, e);
            } else e = -INFINITY;
            sp[i] = e;
        }
#pragma unroll
        for (int o = 32; o > 0; o >>= 1) m = fmaxf(m, __shfl_xor(m, o, 64));
        __syncthreads();
        float ssum = 0.f;
        for (int i = lane; i < deg; i += 64) {
            float p = __expf(sp[i] - m);
            sp[i] = p;
            ssum += p;
        }
#pragma unroll
        for (int o = 32; o > 0; o >>= 1) ssum += __shfl_xor(ssum, o, 64);
        __syncthreads();
        float acc = 0.f;
        for (int i = 0; i < deg; ++i)
            acc = fmaf(sp[i], Wh[(size_t)sdst[i] * OUT_DIM + lane], acc);
        out[(size_t)r * OUT_DIM + lane] = acc / ssum;
    } else {
        float m = -INFINITY;
        for (int i = lane; i < deg; i += 64) {
            int d = csr[beg + i];
            bool first = true;
            for (int j = 0; j < i; ++j)
                if (csr[beg + j] == d) { first = false; break; }
            if (first) {
                float e = er + ed[d];
                e = e > 0.f ? e : ALPHA * e;
                m = fmaxf(m, e);
            }
        }
#pragma unroll
        for (int o = 32; o > 0; o >>= 1) m = fmaxf(m, __shfl_xor(m, o, 64));
        float ssum = 0.f;
        for (int i = lane; i < deg; i += 64) {
            int d = csr[beg + i];
            bool first = true;
            for (int j = 0; j < i; ++j)
                if (csr[beg + j] == d) { first = false; break; }
            if (first) {
                float e = er + ed[d];
                e = e > 0.f ? e : ALPHA * e;
                ssum += __expf(e - m);
            }
        }
#pragma unroll
        for (int o = 32; o > 0; o >>= 1) ssum += __shfl_xor(ssum, o, 64);
        float acc = 0.f;
        for (int i = 0; i < deg; ++i) {
            int d = csr[beg + i];
            bool first = true;
            for (int j = 0; j < i; ++j)
                if (csr[beg + j] == d) { first = false; break; }
            if (first) {
                float e = er + ed[d];
                e = e > 0.f ? e : ALPHA * e;
                acc = fmaf(__expf(e - m), Wh[(size_t)d * OUT_DIM + lane], acc);
            }
        }
        out[(size_t)r * OUT_DIM + lane] = acc / ssum;
    }
}

// ---------------------------------------------------------------------------
extern "C" void kernel_launch(void* const* d_in, const int* in_sizes, int n_in,
                              void* d_out, int out_size, void* d_ws, size_t ws_size,
                              hipStream_t stream) {
    const float* X     = (const float*)d_in[0];
    const int*   edges = (const int*)d_in[1];
    const float* W     = (const float*)d_in[2];
    const float* a     = (const float*)d_in[3];
    float* out = (float*)d_out;

    const int E = in_sizes[1] / 2;
    const int* src = edges;
    const int* dst = edges + E;

    char* ws = (char*)d_ws;
    size_t o = 0;
    auto carve = [&](size_t bytes) -> void* {
        o = (o + 255) & ~(size_t)255;
        void* p = ws + o;
        o += bytes;
        return p;
    };
    float* Wh  = (float*)carve((size_t)N_NODES * OUT_DIM * 4);
    float* es  = (float*)carve((size_t)N_NODES * 4);
    float* ed  = (float*)carve((size_t)N_NODES * 4);
    int*   cur = (int*)carve((size_t)N_NODES * 4);

    size_t slots_off = (o + 255) & ~(size_t)255;
    size_t need_fast = slots_off + (size_t)N_NODES * CAPS * 8;

    if (ws_size >= need_fast) {
        int2* slots = (int2*)(ws + slots_off);
        k_gemm      <<<(N_NODES + 31) / 32, 256, 0, stream>>>(X, W, a, Wh, es, ed, cur);
        k_fill_slots<<<(E + 255) / 256, 256, 0, stream>>>(src, dst, E, es, ed, cur, slots);
        k_attn_slots<<<N_NODES, 64, 0, stream>>>(cur, slots, Wh, out);
    } else {
        int* cnt = (int*)carve((size_t)N_NODES * 4);
        int* off = (int*)carve((size_t)(N_NODES + 1) * 4);
        int* csr = (int*)carve((size_t)E * 4);
        k_gemm <<<(N_NODES + 31) / 32, 256, 0, stream>>>(X, W, a, Wh, es, ed, cnt);
        k_count<<<(E + 255) / 256, 256, 0, stream>>>(src, E, cnt);
        k_scan <<<1, 1024, 0, stream>>>(cnt, off, cur, N_NODES, E);
        k_fill <<<(E + 255) / 256, 256, 0, stream>>>(src, dst, E, cur, csr);
        k_attn <<<N_NODES, 64, 0, stream>>>(off, csr, es, ed, Wh, out);
    }
}

// Round 5
// 65.893 us; speedup vs baseline: 3.6441x; 1.0620x over previous
//
#include <hip/hip_runtime.h>

#define N_NODES 10000
#define IN_DIM  256
#define OUT_DIM 64
#define ALPHA   0.2f
#define CAPS    128   // slot capacity/row (mean deg 32, max ~66; P(>128) ~ 1e-40, clamped)
#define CAP     256   // CSR-fallback LDS edge capacity

// ---------------------------------------------------------------------------
// Kernel 1: Wh = X @ W (10000x256 @ 256x64) + scores es/ed, NO LDS.
// Round-4 lesson: the LDS-staged version was LDS-throughput-bound (~512
// ds_read_b128 x 12cy per wave, all BROADCAST reads — every X element is
// wave-uniform). Here X is read via wave-uniform addresses (wave id forced
// into an SGPR via readfirstlane) so the compiler can scalarize X loads to
// s_load (SMEM pipe), leaving VALU free for the 16 fma/step.
// 625 blocks x 16 rows, 4 rows/wave, lane = out column.
// Also zeroes cur[] for k_fill_slots (saves a fill dispatch).
// Round-3 lesson: do NOT fuse phases with grid.sync() — cooperative sync on
// 8-XCD MI355X stalls everything (69us -> 240us).
// ---------------------------------------------------------------------------
__global__ __launch_bounds__(256) void k_gemm(const float* __restrict__ X,
                                              const float* __restrict__ W,
                                              const float* __restrict__ a,
                                              float* __restrict__ Wh,
                                              float* __restrict__ es,
                                              float* __restrict__ ed,
                                              int* __restrict__ zero10k) {
    const int t = threadIdx.x;
    const int gid = blockIdx.x * 256 + t;
    if (gid < N_NODES) zero10k[gid] = 0;

    const int wave = __builtin_amdgcn_readfirstlane(t >> 6);  // wave-uniform SGPR
    const int lane = t & 63;
    const int row0 = blockIdx.x * 16 + wave * 4;              // 625*16 = 10000 exactly

    const float* __restrict__ x0 = X + (size_t)(row0 + 0) * IN_DIM;
    const float* __restrict__ x1 = X + (size_t)(row0 + 1) * IN_DIM;
    const float* __restrict__ x2 = X + (size_t)(row0 + 2) * IN_DIM;
    const float* __restrict__ x3 = X + (size_t)(row0 + 3) * IN_DIM;

    float acc0 = 0.f, acc1 = 0.f, acc2 = 0.f, acc3 = 0.f;

#pragma unroll 2
    for (int kk = 0; kk < IN_DIM; kk += 4) {
        // per-lane W column loads, 256B coalesced, L1/L2-resident
        float w0 = W[(kk + 0) * OUT_DIM + lane];
        float w1 = W[(kk + 1) * OUT_DIM + lane];
        float w2 = W[(kk + 2) * OUT_DIM + lane];
        float w3 = W[(kk + 3) * OUT_DIM + lane];
        // wave-uniform X loads (scalarizable -> s_load_dwordx4)
        float4 a0 = *(const float4*)(x0 + kk);
        float4 a1 = *(const float4*)(x1 + kk);
        float4 a2 = *(const float4*)(x2 + kk);
        float4 a3 = *(const float4*)(x3 + kk);

        acc0 = fmaf(a0.x, w0, acc0); acc0 = fmaf(a0.y, w1, acc0);
        acc0 = fmaf(a0.z, w2, acc0); acc0 = fmaf(a0.w, w3, acc0);
        acc1 = fmaf(a1.x, w0, acc1); acc1 = fmaf(a1.y, w1, acc1);
        acc1 = fmaf(a1.z, w2, acc1); acc1 = fmaf(a1.w, w3, acc1);
        acc2 = fmaf(a2.x, w0, acc2); acc2 = fmaf(a2.y, w1, acc2);
        acc2 = fmaf(a2.z, w2, acc2); acc2 = fmaf(a2.w, w3, acc2);
        acc3 = fmaf(a3.x, w0, acc3); acc3 = fmaf(a3.y, w1, acc3);
        acc3 = fmaf(a3.z, w2, acc3); acc3 = fmaf(a3.w, w3, acc3);
    }

    const float asrc = a[lane];
    const float adst = a[OUT_DIM + lane];
    float accs[4] = {acc0, acc1, acc2, acc3};
#pragma unroll
    for (int r4 = 0; r4 < 4; ++r4) {
        int row = row0 + r4;
        float v = accs[r4];
        Wh[(size_t)row * OUT_DIM + lane] = v;
        float s1 = v * asrc, s2 = v * adst;
#pragma unroll
        for (int o = 32; o > 0; o >>= 1) {
            s1 += __shfl_xor(s1, o, 64);
            s2 += __shfl_xor(s2, o, 64);
        }
        if (lane == 0) { es[row] = s1; ed[row] = s2; }
    }
}

// ---------------------------------------------------------------------------
// Kernel 2: scatter edges into fixed-stride per-row buckets, storing the
// FINISHED score {dst, e = leakyrelu(es[s]+ed[d])}. es/ed 40KB, cache-resident.
// ---------------------------------------------------------------------------
__global__ void k_fill_slots(const int* __restrict__ src, const int* __restrict__ dst,
                             int E, const float* __restrict__ es,
                             const float* __restrict__ ed,
                             int* __restrict__ cur, int2* __restrict__ slots) {
    int i = blockIdx.x * 256 + threadIdx.x;
    if (i < E) {
        int s = src[i], d = dst[i];
        float e = es[s] + ed[d];
        e = e > 0.f ? e : ALPHA * e;
        int p = atomicAdd(&cur[s], 1);
        if (p < CAPS) slots[(size_t)s * CAPS + p] = make_int2(d, __float_as_int(e));
    }
}

// ---------------------------------------------------------------------------
// Kernel 3: one wave per row. Dedupe duplicate (src,dst) pairs (reference
// .at[].set counts each unique pair ONCE; duplicate e identical), softmax,
// h' = sum p_i/S * Wh[dst_i,:]. lane = out dim -> 256B coalesced Wh gathers.
// ---------------------------------------------------------------------------
__global__ __launch_bounds__(64) void k_attn_slots(const int* __restrict__ cur,
                                                   const int2* __restrict__ slots,
                                                   const float* __restrict__ Wh,
                                                   float* __restrict__ out) {
    const int r = blockIdx.x;
    const int lane = threadIdx.x;
    int deg = cur[r];
    if (deg > CAPS) deg = CAPS;

    if (deg == 0) {
        // softmax of all-NEG_FILL row is uniform -> column mean of Wh
        float acc = 0.f;
        for (int j = 0; j < N_NODES; ++j) acc += Wh[(size_t)j * OUT_DIM + lane];
        out[(size_t)r * OUT_DIM + lane] = acc / (float)N_NODES;
        return;
    }

    __shared__ int   sdst[CAPS];
    __shared__ float sp[CAPS];

    // pass A: load finished slot pairs
    for (int i = lane; i < deg; i += 64) {
        int2 v = slots[(size_t)r * CAPS + i];
        sdst[i] = v.x;
        sp[i]   = __int_as_float(v.y);
    }
    __syncthreads();

    // pass B: dedupe-mark + row max
    float m = -INFINITY;
    for (int i = lane; i < deg; i += 64) {
        int d = sdst[i];
        bool first = true;
        for (int j = 0; j < i; ++j)
            if (sdst[j] == d) { first = false; break; }
        if (first) m = fmaxf(m, sp[i]);
        else       sp[i] = -INFINITY;     // exp() -> 0
    }
#pragma unroll
    for (int o = 32; o > 0; o >>= 1) m = fmaxf(m, __shfl_xor(m, o, 64));
    __syncthreads();

    // pass C: exp + sum
    float ssum = 0.f;
    for (int i = lane; i < deg; i += 64) {
        float p = __expf(sp[i] - m);
        sp[i] = p;
        ssum += p;
    }
#pragma unroll
    for (int o = 32; o > 0; o >>= 1) ssum += __shfl_xor(ssum, o, 64);
    __syncthreads();

    // pass D: accumulate h', 4 gathers in flight
    float acc = 0.f;
    int i = 0;
    for (; i + 4 <= deg; i += 4) {
        float p0 = sp[i + 0], p1 = sp[i + 1], p2 = sp[i + 2], p3 = sp[i + 3];
        int   q0 = sdst[i + 0], q1 = sdst[i + 1], q2 = sdst[i + 2], q3 = sdst[i + 3];
        float w0 = Wh[(size_t)q0 * OUT_DIM + lane];
        float w1 = Wh[(size_t)q1 * OUT_DIM + lane];
        float w2 = Wh[(size_t)q2 * OUT_DIM + lane];
        float w3 = Wh[(size_t)q3 * OUT_DIM + lane];
        acc = fmaf(p0, w0, acc);
        acc = fmaf(p1, w1, acc);
        acc = fmaf(p2, w2, acc);
        acc = fmaf(p3, w3, acc);
    }
    for (; i < deg; ++i)
        acc = fmaf(sp[i], Wh[(size_t)sdst[i] * OUT_DIM + lane], acc);

    out[(size_t)r * OUT_DIM + lane] = acc / ssum;
}

// ---------------------------------------------------------------------------
// CSR FALLBACK (only if ws can't hold the slot buckets).
// ---------------------------------------------------------------------------
__global__ void k_count(const int* __restrict__ src, int E, int* __restrict__ cnt) {
    int i = blockIdx.x * 256 + threadIdx.x;
    if (i < E) atomicAdd(&cnt[src[i]], 1);
}

__global__ __launch_bounds__(1024) void k_scan(const int* __restrict__ cnt,
                                               int* __restrict__ off,
                                               int* __restrict__ cur,
                                               int n, int E) {
    __shared__ int part[1024];
    const int t = threadIdx.x;
    const int CH = (N_NODES + 1023) / 1024;
    int beg = t * CH, end = min(beg + CH, n);
    int s = 0;
    for (int i = beg; i < end; ++i) s += cnt[i];
    part[t] = s;
    __syncthreads();
    for (int d = 1; d < 1024; d <<= 1) {
        int v = (t >= d) ? part[t - d] : 0;
        __syncthreads();
        part[t] += v;
        __syncthreads();
    }
    int run = (t == 0) ? 0 : part[t - 1];
    for (int i = beg; i < end; ++i) {
        off[i] = run;
        cur[i] = run;
        run += cnt[i];
    }
    if (t == 0) off[n] = E;
}

__global__ void k_fill(const int* __restrict__ src, const int* __restrict__ dst, int E,
                       int* __restrict__ cur, int* __restrict__ csr) {
    int i = blockIdx.x * 256 + threadIdx.x;
    if (i < E) {
        int p = atomicAdd(&cur[src[i]], 1);
        csr[p] = dst[i];
    }
}

__global__ __launch_bounds__(64) void k_attn(const int* __restrict__ off,
                                             const int* __restrict__ csr,
                                             const float* __restrict__ es,
                                             const float* __restrict__ ed,
                                             const float* __restrict__ Wh,
                                             float* __restrict__ out) {
    const int r = blockIdx.x;
    const int lane = threadIdx.x;
    const int beg = off[r];
    const int deg = off[r + 1] - beg;
    if (deg == 0) {
        float acc = 0.f;
        for (int j = 0; j < N_NODES; ++j) acc += Wh[(size_t)j * OUT_DIM + lane];
        out[(size_t)r * OUT_DIM + lane] = acc / (float)N_NODES;
        return;
    }
    const float er = es[r];
    __shared__ int   sdst[CAP];
    __shared__ float sp[CAP];
    if (deg <= CAP) {
        for (int i = lane; i < deg; i += 64) sdst[i] = csr[beg + i];
        __syncthreads();
        float m = -INFINITY;
        for (int i = lane; i < deg; i += 64) {
            int d = sdst[i];
            bool first = true;
            for (int j = 0; j < i; ++j)
                if (sdst[j] == d) { first = false; break; }
            float e;
            if (first) {
                e = er + ed[d];
                e = e > 0.f ? e : ALPHA * e;
                m = fmaxf(m, e);
            } else e = -INFINITY;
            sp[i] = e;
        }
#pragma unroll
        for (int o = 32; o > 0; o >>= 1) m = fmaxf(m, __shfl_xor(m, o, 64));
        __syncthreads();
        float ssum = 0.f;
        for (int i = lane; i < deg; i += 64) {
            float p = __expf(sp[i] - m);
            sp[i] = p;
            ssum += p;
        }
#pragma unroll
        for (int o = 32; o > 0; o >>= 1) ssum += __shfl_xor(ssum, o, 64);
        __syncthreads();
        float acc = 0.f;
        for (int i = 0; i < deg; ++i)
            acc = fmaf(sp[i], Wh[(size_t)sdst[i] * OUT_DIM + lane], acc);
        out[(size_t)r * OUT_DIM + lane] = acc / ssum;
    } else {
        float m = -INFINITY;
        for (int i = lane; i < deg; i += 64) {
            int d = csr[beg + i];
            bool first = true;
            for (int j = 0; j < i; ++j)
                if (csr[beg + j] == d) { first = false; break; }
            if (first) {
                float e = er + ed[d];
                e = e > 0.f ? e : ALPHA * e;
                m = fmaxf(m, e);
            }
        }
#pragma unroll
        for (int o = 32; o > 0; o >>= 1) m = fmaxf(m, __shfl_xor(m, o, 64));
        float ssum = 0.f;
        for (int i = lane; i < deg; i += 64) {
            int d = csr[beg + i];
            bool first = true;
            for (int j = 0; j < i; ++j)
                if (csr[beg + j] == d) { first = false; break; }
            if (first) {
                float e = er + ed[d];
                e = e > 0.f ? e : ALPHA * e;
                ssum += __expf(e - m);
            }
        }
#pragma unroll
        for (int o = 32; o > 0; o >>= 1) ssum += __shfl_xor(ssum, o, 64);
        float acc = 0.f;
        for (int i = 0; i < deg; ++i) {
            int d = csr[beg + i];
            bool first = true;
            for (int j = 0; j < i; ++j)
                if (csr[beg + j] == d) { first = false; break; }
            if (first) {
                float e = er + ed[d];
                e = e > 0.f ? e : ALPHA * e;
                acc = fmaf(__expf(e - m), Wh[(size_t)d * OUT_DIM + lane], acc);
            }
        }
        out[(size_t)r * OUT_DIM + lane] = acc / ssum;
    }
}

// ---------------------------------------------------------------------------
extern "C" void kernel_launch(void* const* d_in, const int* in_sizes, int n_in,
                              void* d_out, int out_size, void* d_ws, size_t ws_size,
                              hipStream_t stream) {
    const float* X     = (const float*)d_in[0];
    const int*   edges = (const int*)d_in[1];
    const float* W     = (const float*)d_in[2];
    const float* a     = (const float*)d_in[3];
    float* out = (float*)d_out;

    const int E = in_sizes[1] / 2;
    const int* src = edges;
    const int* dst = edges + E;

    char* ws = (char*)d_ws;
    size_t o = 0;
    auto carve = [&](size_t bytes) -> void* {
        o = (o + 255) & ~(size_t)255;
        void* p = ws + o;
        o += bytes;
        return p;
    };
    float* Wh  = (float*)carve((size_t)N_NODES * OUT_DIM * 4);
    float* es  = (float*)carve((size_t)N_NODES * 4);
    float* ed  = (float*)carve((size_t)N_NODES * 4);
    int*   cur = (int*)carve((size_t)N_NODES * 4);

    size_t slots_off = (o + 255) & ~(size_t)255;
    size_t need_fast = slots_off + (size_t)N_NODES * CAPS * 8;

    if (ws_size >= need_fast) {
        int2* slots = (int2*)(ws + slots_off);
        k_gemm      <<<625, 256, 0, stream>>>(X, W, a, Wh, es, ed, cur);
        k_fill_slots<<<(E + 255) / 256, 256, 0, stream>>>(src, dst, E, es, ed, cur, slots);
        k_attn_slots<<<N_NODES, 64, 0, stream>>>(cur, slots, Wh, out);
    } else {
        int* cnt = (int*)carve((size_t)N_NODES * 4);
        int* off = (int*)carve((size_t)(N_NODES + 1) * 4);
        int* csr = (int*)carve((size_t)E * 4);
        k_gemm <<<625, 256, 0, stream>>>(X, W, a, Wh, es, ed, cnt);
        k_count<<<(E + 255) / 256, 256, 0, stream>>>(src, E, cnt);
        k_scan <<<1, 1024, 0, stream>>>(cnt, off, cur, N_NODES, E);
        k_fill <<<(E + 255) / 256, 256, 0, stream>>>(src, dst, E, cur, csr);
        k_attn <<<N_NODES, 64, 0, stream>>>(off, csr, es, ed, Wh, out);
    }
}